// Round 1
// baseline (624.480 us; speedup 1.0000x reference)
//
#include <hip/hip_runtime.h>
#include <cfloat>

// Problem constants (fixed by setup_inputs)
#define THRV 0.2f
#define H0 60
#define W0 80
#define H1 60
#define W1 80
#define LL (H0 * W0)   // 4800
#define SS (H1 * W1)   // 4800
#define BR 2           // border_rm

// ---------------------------------------------------------------------------
// Pass 1: per-column max over L rows. conf >= 0, so uint bit-pattern compare
// is order-preserving; atomicMax on uint. colmax ws must be zeroed first.
// ---------------------------------------------------------------------------
__global__ void __launch_bounds__(256) colmax_kernel(
    const float* __restrict__ conf, unsigned int* __restrict__ colmax,
    int rowsPerBlock) {
  int s = blockIdx.x * 256 + threadIdx.x;
  if (s >= SS) return;
  int n = blockIdx.z;
  int l0 = blockIdx.y * rowsPerBlock;
  int l1 = min(l0 + rowsPerBlock, LL);
  const float* p = conf + ((size_t)n * LL + l0) * SS + s;
  float m = 0.0f;
  for (int l = l0; l < l1; ++l) {
    m = fmaxf(m, *p);
    p += SS;
  }
  atomicMax(&colmax[n * SS + s], __float_as_uint(m));
}

// ---------------------------------------------------------------------------
// Pass 2: one block per (n, l) row. Stage row in LDS + reduce rowmax, then
// find first s with full mask condition (thr, valid1, rowmax-eq, colmax-eq).
// Border-invalid rows short-circuit to zeros (11% traffic saved).
// ---------------------------------------------------------------------------
__global__ void __launch_bounds__(256) row_kernel(
    const float* __restrict__ conf, const unsigned int* __restrict__ colmax,
    float* __restrict__ out, int N) {
  int l = blockIdx.x;
  int n = blockIdx.y;
  int tid = threadIdx.x;
  const int NL = N * LL;

  int r0 = l / W0, c0 = l % W0;
  bool valid0 = (r0 >= BR) && (r0 < H0 - BR) && (c0 >= BR) && (c0 < W0 - BR);
  if (!valid0) {
    if (tid == 0) {
      out[n * LL + l] = 0.0f;            // mconf
      out[NL + n * LL + l] = 0.0f;       // mask_v
      out[2 * NL + n * LL + l] = 0.0f;   // all_j_ids
    }
    return;
  }

  __shared__ float row[SS];      // 19.2 KB
  __shared__ float wmax[4];
  __shared__ int s_minidx;

  const float* p = conf + ((size_t)n * LL + l) * SS;
  float m = -FLT_MAX;
  for (int s = tid; s < SS; s += 256) {
    float v = p[s];
    row[s] = v;
    m = fmaxf(m, v);
  }
  // wave64 max-reduce, then cross-wave via LDS
  for (int off = 32; off > 0; off >>= 1) m = fmaxf(m, __shfl_down(m, off, 64));
  if ((tid & 63) == 0) wmax[tid >> 6] = m;
  if (tid == 0) s_minidx = 0x7fffffff;
  __syncthreads();
  float rowmax = fmaxf(fmaxf(wmax[0], wmax[1]), fmaxf(wmax[2], wmax[3]));

  // Second scan over LDS copy: first index satisfying the full mask.
  // colmax global load only fires where v == rowmax (~1 per row, L2-hot).
  if (rowmax > THRV) {
    const unsigned int* cm = colmax + n * SS;
    for (int s = tid; s < SS; s += 256) {
      float v = row[s];
      if (v == rowmax) {
        int r1 = s / W1, c1 = s % W1;
        bool valid1 = (r1 >= BR) && (r1 < H1 - BR) && (c1 >= BR) && (c1 < W1 - BR);
        if (valid1 && v == __uint_as_float(cm[s])) atomicMin(&s_minidx, s);
      }
    }
  }
  __syncthreads();

  if (tid == 0) {
    int j = s_minidx;
    bool found = (j != 0x7fffffff);
    out[n * LL + l] = found ? rowmax : 0.0f;            // mconf = conf[l, j]
    out[NL + n * LL + l] = found ? 1.0f : 0.0f;         // mask_v
    out[2 * NL + n * LL + l] = found ? (float)j : 0.0f; // all_j_ids (argmax->0 if none)
  }
}

extern "C" void kernel_launch(void* const* d_in, const int* in_sizes, int n_in,
                              void* d_out, int out_size, void* d_ws, size_t ws_size,
                              hipStream_t stream) {
  const float* conf = (const float*)d_in[0];
  int N = in_sizes[0] / (LL * SS);  // 4
  float* out = (float*)d_out;
  unsigned int* colmax = (unsigned int*)d_ws;  // N*SS uints = 76.8 KB

  hipMemsetAsync(colmax, 0, (size_t)N * SS * sizeof(unsigned int), stream);

  // Pass 1: 19 col-tiles x 25 row-chunks x N = 1900 blocks
  const int L_CHUNKS = 25;
  dim3 g1((SS + 255) / 256, L_CHUNKS, N);
  colmax_kernel<<<g1, 256, 0, stream>>>(conf, colmax, (LL + L_CHUNKS - 1) / L_CHUNKS);

  // Pass 2: one block per row
  dim3 g2(LL, N);
  row_kernel<<<g2, 256, 0, stream>>>(conf, colmax, out, N);
}

// Round 2
// 594.524 us; speedup vs baseline: 1.0504x; 1.0504x over previous
//
#include <hip/hip_runtime.h>
#include <cfloat>

// Problem constants (fixed by setup_inputs)
#define THRV 0.2f
#define H0 60
#define W0 80
#define H1 60
#define W1 80
#define LL (H0 * W0)   // 4800
#define SS (H1 * W1)   // 4800
#define BR 2           // border_rm
#define KCAND 8        // max recorded rowmax-tie candidates per row
#define RPB 12         // rows per block in fused kernel -> 4800/12=400 blocks per n

// ---------------------------------------------------------------------------
// Fused single-read pass. Block = 256 threads, processes RPB consecutive rows.
// Per row: load 4800 floats as 5 strided float4 per thread (held in REGISTERS),
// reduce rowmax, rescan registers for tie candidates (v == rowmax). Per-thread
// column-max partials accumulate in registers across all RPB rows, flushed once
// at the end via atomicMax (uint bit-pattern, valid for floats >= 0).
// ---------------------------------------------------------------------------
__global__ void __launch_bounds__(256) fused_scan(
    const float* __restrict__ conf,
    unsigned int* __restrict__ colmax,   // [N*SS], pre-zeroed
    float* __restrict__ rowmaxArr,       // [N*LL]
    int* __restrict__ candCnt,           // [N*LL]
    int* __restrict__ candPos)           // [N*LL*KCAND]
{
  const int tid = threadIdx.x;
  const int n = blockIdx.y;
  const int l0 = blockIdx.x * RPB;

  __shared__ float wred[4];
  __shared__ int lcnt;
  __shared__ int lpos[KCAND];
  if (tid == 0) lcnt = 0;

  float4 cm[5];
#pragma unroll
  for (int k = 0; k < 5; ++k) cm[k] = make_float4(0.f, 0.f, 0.f, 0.f);
  __syncthreads();  // lcnt init visible before first row's atomicAdd

  for (int r = 0; r < RPB; ++r) {
    const int l = l0 + r;
    const float4* rowp = (const float4*)(conf + ((size_t)n * LL + l) * SS);

    float4 d[5];
    float tm = -1.f;
#pragma unroll
    for (int k = 0; k < 5; ++k) {
      const int i = tid + 256 * k;   // float4 index; 1200 float4 == 4800 floats exactly
      if (i < 1200) {
        float4 v = rowp[i];
        d[k] = v;
        cm[k].x = fmaxf(cm[k].x, v.x);
        cm[k].y = fmaxf(cm[k].y, v.y);
        cm[k].z = fmaxf(cm[k].z, v.z);
        cm[k].w = fmaxf(cm[k].w, v.w);
        tm = fmaxf(tm, fmaxf(fmaxf(v.x, v.y), fmaxf(v.z, v.w)));
      } else {
        d[k] = make_float4(-1.f, -1.f, -1.f, -1.f);  // never matches rowmax > THR
      }
    }

    // wave64 butterfly max, then cross-wave via LDS
#pragma unroll
    for (int off = 32; off; off >>= 1) tm = fmaxf(tm, __shfl_xor(tm, off, 64));
    if ((tid & 63) == 0) wred[tid >> 6] = tm;
    __syncthreads();  // b1: wred visible (also orders lcnt reset before atomicAdd)
    const float rowmax = fmaxf(fmaxf(wred[0], wred[1]), fmaxf(wred[2], wred[3]));

    const int r0 = l / W0, c0 = l % W0;
    const bool valid0 = (r0 >= BR) && (r0 < H0 - BR) && (c0 >= BR) && (c0 < W0 - BR);

    if (valid0 && rowmax > THRV) {
#pragma unroll
      for (int k = 0; k < 5; ++k) {
        const int i = tid + 256 * k;
        const float4 v = d[k];
        if (v.x == rowmax) { int ix = atomicAdd(&lcnt, 1); if (ix < KCAND) lpos[ix] = 4 * i + 0; }
        if (v.y == rowmax) { int ix = atomicAdd(&lcnt, 1); if (ix < KCAND) lpos[ix] = 4 * i + 1; }
        if (v.z == rowmax) { int ix = atomicAdd(&lcnt, 1); if (ix < KCAND) lpos[ix] = 4 * i + 2; }
        if (v.w == rowmax) { int ix = atomicAdd(&lcnt, 1); if (ix < KCAND) lpos[ix] = 4 * i + 3; }
      }
    }
    __syncthreads();  // b2: lcnt/lpos final for this row

    const int row = n * LL + l;
    const int c = lcnt;
    if (tid == 0) { candCnt[row] = c; rowmaxArr[row] = rowmax; }
    if (tid < (c < KCAND ? c : KCAND)) candPos[row * KCAND + tid] = lpos[tid];
    __syncthreads();  // b3: all reads of lcnt/lpos done before reset
    if (tid == 0) lcnt = 0;  // ordered before next row's atomicAdd by next b1
  }

  // Flush per-thread column-max partials (each column owned by exactly one thread)
#pragma unroll
  for (int k = 0; k < 5; ++k) {
    const int i = tid + 256 * k;
    if (i < 1200) {
      unsigned int* base = colmax + n * SS + 4 * i;
      atomicMax(base + 0, __float_as_uint(cm[k].x));
      atomicMax(base + 1, __float_as_uint(cm[k].y));
      atomicMax(base + 2, __float_as_uint(cm[k].z));
      atomicMax(base + 3, __float_as_uint(cm[k].w));
    }
  }
}

// ---------------------------------------------------------------------------
// Tiny resolve pass: one thread per (n,l) row. Min candidate s passing
// valid1 && colmax bit-equality == first-True argmax of the reference.
// ---------------------------------------------------------------------------
__global__ void __launch_bounds__(256) resolve(
    const float* __restrict__ conf,
    const unsigned int* __restrict__ colmax,
    const float* __restrict__ rowmaxArr,
    const int* __restrict__ candCnt,
    const int* __restrict__ candPos,
    float* __restrict__ out, int N)
{
  const int row = blockIdx.x * 256 + threadIdx.x;
  const int NL = N * LL;
  if (row >= NL) return;
  const int n = row / LL;

  float mconf = 0.f, mv = 0.f, jid = 0.f;
  const int c = candCnt[row];
  if (c > 0) {
    const float rowmax = rowmaxArr[row];
    const unsigned int rmu = __float_as_uint(rowmax);
    const unsigned int* cmn = colmax + n * SS;
    int best = 0x7fffffff;
    if (c <= KCAND) {
      for (int i = 0; i < c; ++i) {
        const int s = candPos[row * KCAND + i];
        const int r1 = s / W1, c1 = s % W1;
        const bool valid1 = (r1 >= BR) && (r1 < H1 - BR) && (c1 >= BR) && (c1 < W1 - BR);
        if (valid1 && cmn[s] == rmu && s < best) best = s;
      }
    } else {
      // >KCAND exact-float ties at rowmax: rescan this row serially (near-impossible path)
      const float* rp = conf + (size_t)row * SS;
      for (int s = 0; s < SS; ++s) {
        if (rp[s] == rowmax) {
          const int r1 = s / W1, c1 = s % W1;
          const bool valid1 = (r1 >= BR) && (r1 < H1 - BR) && (c1 >= BR) && (c1 < W1 - BR);
          if (valid1 && cmn[s] == rmu) { best = s; break; }
        }
      }
    }
    if (best != 0x7fffffff) { mconf = rowmax; mv = 1.f; jid = (float)best; }
  }
  out[row] = mconf;             // mconf
  out[NL + row] = mv;           // mask_v
  out[2 * NL + row] = jid;      // all_j_ids
}

extern "C" void kernel_launch(void* const* d_in, const int* in_sizes, int n_in,
                              void* d_out, int out_size, void* d_ws, size_t ws_size,
                              hipStream_t stream) {
  const float* conf = (const float*)d_in[0];
  const int N = in_sizes[0] / (LL * SS);  // 4
  float* out = (float*)d_out;

  // Workspace layout (all 4-byte types)
  unsigned int* colmax = (unsigned int*)d_ws;            // N*SS
  float* rowmaxArr = (float*)(colmax + (size_t)N * SS);  // N*LL
  int* candCnt = (int*)(rowmaxArr + (size_t)N * LL);     // N*LL
  int* candPos = candCnt + (size_t)N * LL;               // N*LL*KCAND

  hipMemsetAsync(colmax, 0, (size_t)N * SS * sizeof(unsigned int), stream);

  dim3 g1(LL / RPB, N);  // 400 x 4 = 1600 blocks
  fused_scan<<<g1, 256, 0, stream>>>(conf, colmax, rowmaxArr, candCnt, candPos);

  const int NL = N * LL;
  resolve<<<(NL + 255) / 256, 256, 0, stream>>>(conf, colmax, rowmaxArr, candCnt, candPos, out, N);
}

// Round 3
// 522.781 us; speedup vs baseline: 1.1945x; 1.1372x over previous
//
#include <hip/hip_runtime.h>

// Problem constants (fixed by setup_inputs)
#define THRV 0.2f
#define H0 60
#define W0 80
#define H1 60
#define W1 80
#define LL (H0 * W0)   // 4800
#define SS (H1 * W1)   // 4800
#define BR 2
#define KCAND 8        // recorded rowmax-tie candidates per row before rescan fallback
#define RPW 16         // rows per wave
#define WPN (LL / RPW) // 300 waves per batch element
#define NQ4 (SS / 4)   // 1200 float4 per row
#define KMAX 19        // ceil(1200/64) float4 per lane per row

// ---------------------------------------------------------------------------
// Pass 1: wave-autonomous scan. No __syncthreads (avoids the vmcnt(0) drain
// the compiler emits before s_barrier), no global atomics. Each wave owns 16
// consecutive rows of one batch element:
//   - 19 lane-strided float4 loads per row, all outstanding (19KB MLP/wave)
//   - streaming per-lane (max, first-idx, tie-count), 2 interleaved streams
//     to shorten the dependent cndmask chain
//   - wave rowmax via __shfl_xor butterfly; candidates via __ballot
//   - column-max partials in 19 float4 regs, stored coalesced once per wave
// ---------------------------------------------------------------------------
__global__ void __launch_bounds__(256) scan_kernel(
    const float* __restrict__ conf,
    float* __restrict__ colPart,    // [N][WPN][SS] per-wave column-max partials
    float* __restrict__ rowmaxArr,  // [N][LL]
    int* __restrict__ candCnt,      // [N][LL]
    int* __restrict__ candPos)      // [N][LL][KCAND]
{
  const int lane = threadIdx.x & 63;
  const int wid = threadIdx.x >> 6;
  const int n = blockIdx.y;
  const int w = blockIdx.x * 4 + wid;  // wave id in [0, WPN)
  const int l0 = w * RPW;

  float4 cm[KMAX];
#pragma unroll
  for (int k = 0; k < KMAX; ++k) cm[k] = make_float4(0.f, 0.f, 0.f, 0.f);

  for (int r = 0; r < RPW; ++r) {
    const int l = l0 + r;
    const float4* __restrict__ rowp =
        (const float4*)(conf + ((size_t)n * LL + l) * SS);

    // Issue the whole row: 19 independent 1KB-coalesced loads in flight.
    float4 d[KMAX];
#pragma unroll
    for (int k = 0; k < KMAX; ++k) {
      const int q = lane + 64 * k;
      if (q < NQ4) d[k] = rowp[q];
    }

    // Two interleaved streaming argmax chains (A: even k, B: odd k).
    float lmA = -1.f, lmB = -1.f;
    int fiA = 0, fiB = 0, cnA = 0, cnB = 0;
#define UPD(LM, FI, CN, V, S)                          \
  {                                                    \
    const float _v = (V);                              \
    const bool _gt = _v > LM;                          \
    const bool _eq = _v == LM;                         \
    CN = _gt ? 1 : (CN + (_eq ? 1 : 0));               \
    FI = _gt ? (S) : FI;                               \
    LM = _gt ? _v : LM;                                \
  }
#pragma unroll
    for (int k = 0; k < KMAX; ++k) {
      const int q = lane + 64 * k;
      if (q < NQ4) {
        const float4 v = d[k];
        cm[k].x = fmaxf(cm[k].x, v.x);
        cm[k].y = fmaxf(cm[k].y, v.y);
        cm[k].z = fmaxf(cm[k].z, v.z);
        cm[k].w = fmaxf(cm[k].w, v.w);
        const int s0 = 4 * q;
        if (k & 1) {
          UPD(lmB, fiB, cnB, v.x, s0 + 0);
          UPD(lmB, fiB, cnB, v.y, s0 + 1);
          UPD(lmB, fiB, cnB, v.z, s0 + 2);
          UPD(lmB, fiB, cnB, v.w, s0 + 3);
        } else {
          UPD(lmA, fiA, cnA, v.x, s0 + 0);
          UPD(lmA, fiA, cnA, v.y, s0 + 1);
          UPD(lmA, fiA, cnA, v.z, s0 + 2);
          UPD(lmA, fiA, cnA, v.w, s0 + 3);
        }
      }
    }
#undef UPD
    // Merge streams: within-lane min-s at max, total tie count at max.
    float lm;
    int fidx, cnt;
    if (lmA > lmB) {
      lm = lmA; fidx = fiA; cnt = cnA;
    } else if (lmB > lmA) {
      lm = lmB; fidx = fiB; cnt = cnB;
    } else {
      lm = lmA; fidx = min(fiA, fiB); cnt = cnA + cnB;
    }

    // Wave rowmax (butterfly, width 64).
    float rowmax = lm;
#pragma unroll
    for (int off = 32; off; off >>= 1)
      rowmax = fmaxf(rowmax, __shfl_xor(rowmax, off, 64));

    const int r0 = l / W0, c0 = l % W0;
    const bool valid0 =
        (r0 >= BR) && (r0 < H0 - BR) && (c0 >= BR) && (c0 < W0 - BR);

    const bool isc = (lm == rowmax);
    const unsigned long long m = __ballot(isc);
    const unsigned long long mMulti = __ballot(isc && cnt > 1);
    const int row = n * LL + l;
    if (valid0 && rowmax > THRV) {
      const int slot = __popcll(m & ((1ull << lane) - 1ull));
      if (isc && slot < KCAND) candPos[row * KCAND + slot] = fidx;
      if (lane == 0) {
        // within-lane multi-tie -> force rescan (sentinel > KCAND)
        candCnt[row] = mMulti ? 0x7fffffff : (int)__popcll(m);
        rowmaxArr[row] = rowmax;
      }
    } else if (lane == 0) {
      candCnt[row] = 0;
      rowmaxArr[row] = rowmax;
    }
  }

  // Coalesced per-wave column-max partial store (no atomics).
  float4* __restrict__ pp = (float4*)(colPart + ((size_t)n * WPN + w) * SS);
#pragma unroll
  for (int k = 0; k < KMAX; ++k) {
    const int q = lane + 64 * k;
    if (q < NQ4) pp[q] = cm[k];
  }
}

// ---------------------------------------------------------------------------
// Pass 2: column-max over the 300 wave-partials. 23 MB read, coalesced.
// ---------------------------------------------------------------------------
__global__ void __launch_bounds__(256) colreduce_kernel(
    const float* __restrict__ colPart, float* __restrict__ colmax, int N) {
  const int t = blockIdx.x * 256 + threadIdx.x;
  if (t >= N * SS) return;
  const int n = t / SS, s = t % SS;
  const float* __restrict__ p = colPart + (size_t)n * WPN * SS + s;
  float m0 = 0.f, m1 = 0.f, m2 = 0.f, m3 = 0.f;
  for (int w = 0; w < WPN; w += 4) {
    m0 = fmaxf(m0, p[(size_t)w * SS]);
    m1 = fmaxf(m1, p[(size_t)(w + 1) * SS]);
    m2 = fmaxf(m2, p[(size_t)(w + 2) * SS]);
    m3 = fmaxf(m3, p[(size_t)(w + 3) * SS]);
  }
  colmax[t] = fmaxf(fmaxf(m0, m1), fmaxf(m2, m3));
}

// ---------------------------------------------------------------------------
// Pass 3: resolve. Min candidate s passing valid1 && colmax equality ==
// first-True argmax of the reference. Rare paths (>KCAND candidates or
// within-lane exact ties) rescan the row serially.
// ---------------------------------------------------------------------------
__global__ void __launch_bounds__(256) resolve_kernel(
    const float* __restrict__ conf, const float* __restrict__ colmax,
    const float* __restrict__ rowmaxArr, const int* __restrict__ candCnt,
    const int* __restrict__ candPos, float* __restrict__ out, int N) {
  const int row = blockIdx.x * 256 + threadIdx.x;
  const int NL = N * LL;
  if (row >= NL) return;
  const int n = row / LL;

  float mconf = 0.f, mv = 0.f, jid = 0.f;
  const int c = candCnt[row];
  if (c > 0) {
    const float rowmax = rowmaxArr[row];
    const float* __restrict__ cmn = colmax + n * SS;
    int best = 0x7fffffff;
    if (c <= KCAND) {
      for (int i = 0; i < c; ++i) {
        const int s = candPos[row * KCAND + i];
        const int r1 = s / W1, c1 = s % W1;
        const bool valid1 =
            (r1 >= BR) && (r1 < H1 - BR) && (c1 >= BR) && (c1 < W1 - BR);
        if (valid1 && cmn[s] == rowmax && s < best) best = s;
      }
    } else {
      // Rare: exact-float tie overflow; serial first-True rescan of the row.
      const float* __restrict__ rp = conf + (size_t)row * SS;
      for (int s = 0; s < SS; ++s) {
        if (rp[s] == rowmax) {
          const int r1 = s / W1, c1 = s % W1;
          const bool valid1 =
              (r1 >= BR) && (r1 < H1 - BR) && (c1 >= BR) && (c1 < W1 - BR);
          if (valid1 && cmn[s] == rowmax) { best = s; break; }
        }
      }
    }
    if (best != 0x7fffffff) { mconf = rowmax; mv = 1.f; jid = (float)best; }
  }
  out[row] = mconf;         // mconf
  out[NL + row] = mv;       // mask_v
  out[2 * NL + row] = jid;  // all_j_ids
}

extern "C" void kernel_launch(void* const* d_in, const int* in_sizes, int n_in,
                              void* d_out, int out_size, void* d_ws, size_t ws_size,
                              hipStream_t stream) {
  const float* conf = (const float*)d_in[0];
  const int N = in_sizes[0] / (LL * SS);  // 4
  float* out = (float*)d_out;

  // Workspace layout (4-byte types; all regions fully written before read)
  float* colPart = (float*)d_ws;                          // N*WPN*SS = 23 MB
  float* colmax = colPart + (size_t)N * WPN * SS;         // N*SS
  float* rowmaxArr = colmax + (size_t)N * SS;             // N*LL
  int* candCnt = (int*)(rowmaxArr + (size_t)N * LL);      // N*LL
  int* candPos = candCnt + (size_t)N * LL;                // N*LL*KCAND

  dim3 g1(WPN / 4, N);  // 75 x 4 blocks, 4 waves each -> 1200 waves
  scan_kernel<<<g1, 256, 0, stream>>>(conf, colPart, rowmaxArr, candCnt, candPos);

  const int NS = N * SS;
  colreduce_kernel<<<(NS + 255) / 256, 256, 0, stream>>>(colPart, colmax, N);

  const int NL = N * LL;
  resolve_kernel<<<(NL + 255) / 256, 256, 0, stream>>>(conf, colmax, rowmaxArr,
                                                       candCnt, candPos, out, N);
}